// Round 3
// baseline (81.450 us; speedup 1.0000x reference)
//
#include <hip/hip_runtime.h>
#include <math.h>

#define BB 8
#define NN 2048
#define IND 128
#define OUTD 64
#define NEG 0.2f

typedef __attribute__((ext_vector_type(4))) float f32x4;
typedef __attribute__((ext_vector_type(2))) _Float16 h2;
typedef __attribute__((ext_vector_type(8))) _Float16 half8;

// f32 -> f16 bits (RNE via cast)
__device__ __forceinline__ unsigned short f2h(float f) {
    union { _Float16 h; unsigned short u; } c;
    c.h = (_Float16)f;
    return c.u;
}

// ---------------------------------------------------------------------------
// Kernel 1 (MFMA): hp = h@W + b ; s = hp@a_src ; F=exp(d), H=exp(NEG*d)
//   - A-frags (h) load DIRECTLY from global (frag k-layout = 8 consecutive f32)
//   - W staged once/block into LDS transposed [o][k] as f16 hi/lo pair
//   - 3-MFMA split (hi*hi + hi*lo + lo*hi, f32 acc, bias in C-init): ~f32-exact
// 512 thr / 64 rows / block, grid 256. Unchanged from round 2.
// ---------------------------------------------------------------------------
__global__ __launch_bounds__(512) void gat_proj_kernel(
    const float* __restrict__ h, const float* __restrict__ W,
    const float* __restrict__ bfc, const float* __restrict__ asrc,
    const float* __restrict__ adst,
    unsigned short* __restrict__ hpT2, float* __restrict__ s,
    _Float16* __restrict__ F, _Float16* __restrict__ H)
{
    __shared__ _Float16 WtH[64 * 136];   // [o][k] hi, pad 136
    __shared__ _Float16 WtL[64 * 136];   // [o][k] lo
    __shared__ float sps[64][2];         // s partials per o-half
    __shared__ float spd[64][2];         // d partials per o-half

    const int t    = threadIdx.x;
    const int lane = t & 63;
    const int wv   = t >> 6;             // 0..7
    const int R0   = blockIdx.x * 64;

    const float4* W4 = (const float4*)W;
    #pragma unroll
    for (int i = 0; i < 4; ++i) {
        const int idx = t + i * 512;     // 2048 float4 total
        union { float4 q; float f[4]; } w;
        w.q = W4[idx];
        const int k  = idx >> 4;         // 16 float4 per k-row
        const int o0 = (idx & 15) * 4;
        #pragma unroll
        for (int c = 0; c < 4; ++c) {
            const float v = w.f[c];
            const _Float16 hi = (_Float16)v;
            const _Float16 lo = (_Float16)(v - (float)hi);
            WtH[(o0 + c) * 136 + k] = hi;
            WtL[(o0 + c) * 136 + k] = lo;
        }
    }

    const int rt = wv >> 1;              // row tile (16 rows)
    const int nh = wv & 1;               // o half (32 cols)
    const int m  = lane & 15;
    const int g  = lane >> 4;            // k-group

    const int o_0 = nh * 32 + m;         // ntile 0 col
    const int o_1 = nh * 32 + 16 + m;    // ntile 1 col

    // ---- A-frags direct from global: rows R0+rt*16+m, k = ks*32+g*8+e ----
    const float* hrow = h + (size_t)(R0 + rt * 16 + m) * IND + g * 8;
    half8 ahi[4], alo[4];
    #pragma unroll
    for (int ks = 0; ks < 4; ++ks) {
        union { float4 q; float f[4]; } p0, p1;
        p0.q = *(const float4*)(hrow + ks * 32);
        p1.q = *(const float4*)(hrow + ks * 32 + 4);
        #pragma unroll
        for (int e = 0; e < 4; ++e) {
            const _Float16 hi0 = (_Float16)p0.f[e];
            ahi[ks][e] = hi0;
            alo[ks][e] = (_Float16)(p0.f[e] - (float)hi0);
            const _Float16 hi1 = (_Float16)p1.f[e];
            ahi[ks][4 + e] = hi1;
            alo[ks][4 + e] = (_Float16)(p1.f[e] - (float)hi1);
        }
    }

    // ---- accumulators init with bias (C layout: col=lane&15, row=g*4+r) ----
    f32x4 acc0, acc1;
    {
        const float b0 = bfc[o_0], b1 = bfc[o_1];
        acc0 = (f32x4){b0, b0, b0, b0};
        acc1 = (f32x4){b1, b1, b1, b1};
    }

    __syncthreads();

    #pragma unroll
    for (int ks = 0; ks < 4; ++ks) {
        const int kb = ks * 32 + g * 8;
        const half8 bh0 = *(const half8*)&WtH[o_0 * 136 + kb];
        const half8 bl0 = *(const half8*)&WtL[o_0 * 136 + kb];
        const half8 bh1 = *(const half8*)&WtH[o_1 * 136 + kb];
        const half8 bl1 = *(const half8*)&WtL[o_1 * 136 + kb];

        acc0 = __builtin_amdgcn_mfma_f32_16x16x32_f16(ahi[ks], bh0, acc0, 0, 0, 0);
        acc0 = __builtin_amdgcn_mfma_f32_16x16x32_f16(ahi[ks], bl0, acc0, 0, 0, 0);
        acc0 = __builtin_amdgcn_mfma_f32_16x16x32_f16(alo[ks], bh0, acc0, 0, 0, 0);

        acc1 = __builtin_amdgcn_mfma_f32_16x16x32_f16(ahi[ks], bh1, acc1, 0, 0, 0);
        acc1 = __builtin_amdgcn_mfma_f32_16x16x32_f16(ahi[ks], bl1, acc1, 0, 0, 0);
        acc1 = __builtin_amdgcn_mfma_f32_16x16x32_f16(alo[ks], bh1, acc1, 0, 0, 0);
    }

    // ---- hpT2 chunk-tiled f16 [b][cj][o][8]: lane holds 4 CONSECUTIVE rows ----
    const int b   = R0 >> 11;
    const int jb0 = (R0 & 2047) + rt * 16 + g * 4;
    const int cj  = jb0 >> 3;
    const int sub = jb0 & 7;             // 0 or 4
    unsigned short* cbase = hpT2 + (((size_t)(b * 256 + cj)) * OUTD) * 8;
    {
        ushort4 u;
        u.x = f2h(acc0[0]); u.y = f2h(acc0[1]);
        u.z = f2h(acc0[2]); u.w = f2h(acc0[3]);
        *(ushort4*)(cbase + o_0 * 8 + sub) = u;
        u.x = f2h(acc1[0]); u.y = f2h(acc1[1]);
        u.z = f2h(acc1[2]); u.w = f2h(acc1[3]);
        *(ushort4*)(cbase + o_1 * 8 + sub) = u;
    }

    // ---- s, d partials over this wave's 32 cols, reduce across 16 lanes ----
    const float a_s0 = asrc[o_0], a_s1 = asrc[o_1];
    const float a_d0 = adst[o_0], a_d1 = adst[o_1];
    float ps[4], pd[4];
    #pragma unroll
    for (int r = 0; r < 4; ++r) {
        ps[r] = acc0[r] * a_s0 + acc1[r] * a_s1;
        pd[r] = acc0[r] * a_d0 + acc1[r] * a_d1;
    }
    #pragma unroll
    for (int msk = 1; msk <= 8; msk <<= 1) {
        #pragma unroll
        for (int r = 0; r < 4; ++r) {
            ps[r] += __shfl_xor(ps[r], msk);
            pd[r] += __shfl_xor(pd[r], msk);
        }
    }
    if (m == 0) {
        #pragma unroll
        for (int r = 0; r < 4; ++r) {
            const int row = rt * 16 + g * 4 + r;
            sps[row][nh] = ps[r];
            spd[row][nh] = pd[r];
        }
    }
    __syncthreads();
    if (t < 64) {
        const float sv = sps[t][0] + sps[t][1];
        const float dv = spd[t][0] + spd[t][1];
        s[R0 + t] = sv;
        F[R0 + t] = (_Float16)__expf(dv);
        H[R0 + t] = (_Float16)__expf(NEG * dv);
    }
}

// ---------------------------------------------------------------------------
// Kernel 2: softmax(leakyrelu(s_i+d_j+b)) @ hp via f16 MFMA.
// Main loop unchanged (8 waves, j-split x8, packed-f16 weights, ones-B MFMA
// denominator). EPILOGUE REWORKED — it was LDS-pipe-bound on scalar b32:
//   - partials stored PERMUTED [row][m*4+ot] (stride 72, 16B-aligned) so
//     stage1 = 16 ds_write_b128 (was 64 b32), stage2 = 16 b128 RMW (was 64+64)
//   - denominator partials folded once per row into llsum[] by wave 0
//     (overlapped with waves 1-3's adds); epilogue reads 1 broadcast/row
//     instead of 8
//   - final read is b128 (4 stored idx = output cols {0,16,32,48}+q; stores
//     stay 64B-coalesced per (ot,row))
// ---------------------------------------------------------------------------
__global__ __launch_bounds__(512) void gat_attn_kernel(
    const unsigned short* __restrict__ hpT2, const float* __restrict__ s,
    const _Float16* __restrict__ F, const _Float16* __restrict__ H,
    const float* __restrict__ battn_p, float* __restrict__ out)
{
    __shared__ float accl[4][64 * 72];   // 73.7 KB, permuted [row][m*4+ot]
    __shared__ float ll[8][64];          // per-wave denominator partials
    __shared__ float llsum[64];          // folded denominators

    const int t    = threadIdx.x;
    const int lane = t & 63;
    const int wv   = t >> 6;             // 0..7
    const int blk  = blockIdx.x;         // 0..255
    const int b    = blk >> 5;           // 32 row-groups per batch
    const int i0   = (blk & 31) * 64;
    const int m    = lane & 15;
    const int kc   = lane >> 4;          // k-chunk quad (0..3)

    const float battn = battn_p[0];
    h2 E2[4], G2[4];
    #pragma unroll
    for (int T = 0; T < 4; ++T) {
        const float smv = s[b * NN + i0 + T * 16 + m] + battn;
        const float Ef = __expf(smv);
        const float Gf = __expf(NEG * smv);
        E2[T] = (h2){(_Float16)Ef, (_Float16)Ef};
        G2[T] = (h2){(_Float16)Gf, (_Float16)Gf};
    }
    const _Float16* Fb = F + b * NN;
    const _Float16* Hb = H + b * NN;
    const _Float16* hb = (const _Float16*)hpT2 + (size_t)b * 256 * OUTD * 8;

    half8 ones;
    #pragma unroll
    for (int q = 0; q < 8; ++q) ones[q] = (_Float16)1.0f;

    f32x4 acc[4][4];                     // [tile][ot]
    f32x4 dacc[4];                       // [tile] denominator
    #pragma unroll
    for (int T = 0; T < 4; ++T) {
        dacc[T] = (f32x4){0.f, 0.f, 0.f, 0.f};
        #pragma unroll
        for (int ot = 0; ot < 4; ++ot) acc[T][ot] = (f32x4){0.f, 0.f, 0.f, 0.f};
    }

    const int jbase = wv * (NN / 8);     // this wave's 256-wide j range

    #pragma unroll 2
    for (int it = 0; it < NN / 8 / 32; ++it) {
        const int j0 = jbase + it * 32;
        // --- B-frags first (longest latency): hp[j0+kc*8..+7][ot*16+m] ---
        const size_t cb = ((size_t)((j0 >> 3) + kc)) * OUTD * 8;
        const half8 bf0 = *(const half8*)(hb + cb + (0 * 16 + m) * 8);
        const half8 bf1 = *(const half8*)(hb + cb + (1 * 16 + m) * 8);
        const half8 bf2 = *(const half8*)(hb + cb + (2 * 16 + m) * 8);
        const half8 bf3 = *(const half8*)(hb + cb + (3 * 16 + m) * 8);

        union { float4 q; h2 p[4]; } Ff, Hf;
        Ff.q = *(const float4*)(Fb + j0 + kc * 8);   // 8 f16 F values
        Hf.q = *(const float4*)(Hb + j0 + kc * 8);   // 8 f16 H values

        #pragma unroll
        for (int T = 0; T < 4; ++T) {
            union { half8 v; h2 p[4]; } af;
            af.p[0] = __builtin_elementwise_max(E2[T] * Ff.p[0], G2[T] * Hf.p[0]);
            af.p[1] = __builtin_elementwise_max(E2[T] * Ff.p[1], G2[T] * Hf.p[1]);
            af.p[2] = __builtin_elementwise_max(E2[T] * Ff.p[2], G2[T] * Hf.p[2]);
            af.p[3] = __builtin_elementwise_max(E2[T] * Ff.p[3], G2[T] * Hf.p[3]);

            acc[T][0] = __builtin_amdgcn_mfma_f32_16x16x32_f16(af.v, bf0, acc[T][0], 0, 0, 0);
            acc[T][1] = __builtin_amdgcn_mfma_f32_16x16x32_f16(af.v, bf1, acc[T][1], 0, 0, 0);
            acc[T][2] = __builtin_amdgcn_mfma_f32_16x16x32_f16(af.v, bf2, acc[T][2], 0, 0, 0);
            acc[T][3] = __builtin_amdgcn_mfma_f32_16x16x32_f16(af.v, bf3, acc[T][3], 0, 0, 0);
            dacc[T]   = __builtin_amdgcn_mfma_f32_16x16x32_f16(af.v, ones, dacc[T], 0, 0, 0);
        }
    }

    // denominator partials: D column 0 lives in m==0 lanes; row = kc*4 + reg
    if (m == 0) {
        #pragma unroll
        for (int T = 0; T < 4; ++T)
            #pragma unroll
            for (int r = 0; r < 4; ++r) ll[wv][T * 16 + kc * 4 + r] = dacc[T][r];
    }

    // ---- two-stage combine, b128 permuted layout [row][m*4+ot] ----
    if (wv >= 4) {
        #pragma unroll
        for (int T = 0; T < 4; ++T) {
            #pragma unroll
            for (int r = 0; r < 4; ++r) {
                const int row = T * 16 + kc * 4 + r;
                float4 v;
                v.x = acc[T][0][r]; v.y = acc[T][1][r];
                v.z = acc[T][2][r]; v.w = acc[T][3][r];
                *(float4*)&accl[wv - 4][row * 72 + m * 4] = v;
            }
        }
    }
    __syncthreads();
    if (wv < 4) {
        #pragma unroll
        for (int T = 0; T < 4; ++T) {
            #pragma unroll
            for (int r = 0; r < 4; ++r) {
                const int row = T * 16 + kc * 4 + r;
                float4 v = *(const float4*)&accl[wv][row * 72 + m * 4];
                v.x += acc[T][0][r]; v.y += acc[T][1][r];
                v.z += acc[T][2][r]; v.w += acc[T][3][r];
                *(float4*)&accl[wv][row * 72 + m * 4] = v;
            }
        }
    }
    // wave 0 folds the 8 denominator partials per row (overlaps waves 1-3)
    if (t < 64) {
        llsum[t] = ((ll[0][t] + ll[1][t]) + (ll[2][t] + ll[3][t])) +
                   ((ll[4][t] + ll[5][t]) + (ll[6][t] + ll[7][t]));
    }
    __syncthreads();

    // ---- epilogue: b128 reads, divide, ELU, coalesced stores ----
    // thread handles rows (t>>4) and (t>>4)+32, stored idx q*4..q*4+3
    // stored idx q*4+ot -> output col ot*16+q
    const int q    = t & 15;
    const int row0 = t >> 4;             // 0..31
    float* ob = out + (((size_t)b * NN + i0) * OUTD);
    #pragma unroll
    for (int rr = 0; rr < 2; ++rr) {
        const int row = row0 + rr * 32;
        const float4 v0 = *(const float4*)&accl[0][row * 72 + q * 4];
        const float4 v1 = *(const float4*)&accl[1][row * 72 + q * 4];
        const float4 v2 = *(const float4*)&accl[2][row * 72 + q * 4];
        const float4 v3 = *(const float4*)&accl[3][row * 72 + q * 4];
        const float ls = llsum[row];
        float vv[4];
        vv[0] = (v0.x + v1.x) + (v2.x + v3.x);
        vv[1] = (v0.y + v1.y) + (v2.y + v3.y);
        vv[2] = (v0.z + v1.z) + (v2.z + v3.z);
        vv[3] = (v0.w + v1.w) + (v2.w + v3.w);
        #pragma unroll
        for (int ot = 0; ot < 4; ++ot) {
            float v = vv[ot] / ls;
            v = (v > 0.f) ? v : expm1f(v);
            ob[(size_t)row * OUTD + ot * 16 + q] = v;
        }
    }
}

// ---------------------------------------------------------------------------
extern "C" void kernel_launch(void* const* d_in, const int* in_sizes, int n_in,
                              void* d_out, int out_size, void* d_ws, size_t ws_size,
                              hipStream_t stream)
{
    const float* h     = (const float*)d_in[0];
    const float* W     = (const float*)d_in[1];
    const float* bfc   = (const float*)d_in[2];
    const float* asrc  = (const float*)d_in[3];
    const float* adst  = (const float*)d_in[4];
    const float* battn = (const float*)d_in[5];
    float* out = (float*)d_out;

    unsigned short* hpT2 = (unsigned short*)d_ws;            // 2 MB f16 tiled
    float*     s = (float*)((char*)d_ws + (size_t)BB * NN * OUTD * 2);
    _Float16*  F = (_Float16*)(s + (size_t)BB * NN);
    _Float16*  H = F + (size_t)BB * NN;

    gat_proj_kernel<<<(BB * NN) / 64, 512, 0, stream>>>(h, W, bfc, asrc, adst,
                                                        hpT2, s, F, H);
    gat_attn_kernel<<<BB * (NN / 64), 512, 0, stream>>>(hpT2, s, F, H, battn, out);
}

// Round 4
// 81.184 us; speedup vs baseline: 1.0033x; 1.0033x over previous
//
#include <hip/hip_runtime.h>
#include <math.h>

#define BB 8
#define NN 2048
#define IND 128
#define OUTD 64
#define NEG 0.2f

typedef __attribute__((ext_vector_type(4))) float f32x4;
typedef __attribute__((ext_vector_type(2))) _Float16 h2;
typedef __attribute__((ext_vector_type(8))) _Float16 half8;

// f32 -> f16 bits (RNE via cast)
__device__ __forceinline__ unsigned short f2h(float f) {
    union { _Float16 h; unsigned short u; } c;
    c.h = (_Float16)f;
    return c.u;
}

// ---------------------------------------------------------------------------
// Kernel 1 (MFMA): hp = h@W + b ; s = hp@a_src ; F=exp(d), H=exp(NEG*d)
//   - A-frags (h) load DIRECTLY from global (frag k-layout = 8 consecutive f32)
//   - W staged once/block into LDS transposed [o][k] as f16 hi/lo pair
//   - 3-MFMA split (hi*hi + hi*lo + lo*hi, f32 acc, bias in C-init): ~f32-exact
// 512 thr / 64 rows / block, grid 256. Unchanged (HBM-floor ~1.3us, runs ~2us).
// ---------------------------------------------------------------------------
__global__ __launch_bounds__(512) void gat_proj_kernel(
    const float* __restrict__ h, const float* __restrict__ W,
    const float* __restrict__ bfc, const float* __restrict__ asrc,
    const float* __restrict__ adst,
    unsigned short* __restrict__ hpT2, float* __restrict__ s,
    _Float16* __restrict__ F, _Float16* __restrict__ H)
{
    __shared__ _Float16 WtH[64 * 136];   // [o][k] hi, pad 136
    __shared__ _Float16 WtL[64 * 136];   // [o][k] lo
    __shared__ float sps[64][2];         // s partials per o-half
    __shared__ float spd[64][2];         // d partials per o-half

    const int t    = threadIdx.x;
    const int lane = t & 63;
    const int wv   = t >> 6;             // 0..7
    const int R0   = blockIdx.x * 64;

    const float4* W4 = (const float4*)W;
    #pragma unroll
    for (int i = 0; i < 4; ++i) {
        const int idx = t + i * 512;     // 2048 float4 total
        union { float4 q; float f[4]; } w;
        w.q = W4[idx];
        const int k  = idx >> 4;         // 16 float4 per k-row
        const int o0 = (idx & 15) * 4;
        #pragma unroll
        for (int c = 0; c < 4; ++c) {
            const float v = w.f[c];
            const _Float16 hi = (_Float16)v;
            const _Float16 lo = (_Float16)(v - (float)hi);
            WtH[(o0 + c) * 136 + k] = hi;
            WtL[(o0 + c) * 136 + k] = lo;
        }
    }

    const int rt = wv >> 1;              // row tile (16 rows)
    const int nh = wv & 1;               // o half (32 cols)
    const int m  = lane & 15;
    const int g  = lane >> 4;            // k-group

    const int o_0 = nh * 32 + m;         // ntile 0 col
    const int o_1 = nh * 32 + 16 + m;    // ntile 1 col

    // ---- A-frags direct from global: rows R0+rt*16+m, k = ks*32+g*8+e ----
    const float* hrow = h + (size_t)(R0 + rt * 16 + m) * IND + g * 8;
    half8 ahi[4], alo[4];
    #pragma unroll
    for (int ks = 0; ks < 4; ++ks) {
        union { float4 q; float f[4]; } p0, p1;
        p0.q = *(const float4*)(hrow + ks * 32);
        p1.q = *(const float4*)(hrow + ks * 32 + 4);
        #pragma unroll
        for (int e = 0; e < 4; ++e) {
            const _Float16 hi0 = (_Float16)p0.f[e];
            ahi[ks][e] = hi0;
            alo[ks][e] = (_Float16)(p0.f[e] - (float)hi0);
            const _Float16 hi1 = (_Float16)p1.f[e];
            ahi[ks][4 + e] = hi1;
            alo[ks][4 + e] = (_Float16)(p1.f[e] - (float)hi1);
        }
    }

    // ---- accumulators init with bias (C layout: col=lane&15, row=g*4+r) ----
    f32x4 acc0, acc1;
    {
        const float b0 = bfc[o_0], b1 = bfc[o_1];
        acc0 = (f32x4){b0, b0, b0, b0};
        acc1 = (f32x4){b1, b1, b1, b1};
    }

    __syncthreads();

    #pragma unroll
    for (int ks = 0; ks < 4; ++ks) {
        const int kb = ks * 32 + g * 8;
        const half8 bh0 = *(const half8*)&WtH[o_0 * 136 + kb];
        const half8 bl0 = *(const half8*)&WtL[o_0 * 136 + kb];
        const half8 bh1 = *(const half8*)&WtH[o_1 * 136 + kb];
        const half8 bl1 = *(const half8*)&WtL[o_1 * 136 + kb];

        acc0 = __builtin_amdgcn_mfma_f32_16x16x32_f16(ahi[ks], bh0, acc0, 0, 0, 0);
        acc0 = __builtin_amdgcn_mfma_f32_16x16x32_f16(ahi[ks], bl0, acc0, 0, 0, 0);
        acc0 = __builtin_amdgcn_mfma_f32_16x16x32_f16(alo[ks], bh0, acc0, 0, 0, 0);

        acc1 = __builtin_amdgcn_mfma_f32_16x16x32_f16(ahi[ks], bh1, acc1, 0, 0, 0);
        acc1 = __builtin_amdgcn_mfma_f32_16x16x32_f16(ahi[ks], bl1, acc1, 0, 0, 0);
        acc1 = __builtin_amdgcn_mfma_f32_16x16x32_f16(alo[ks], bh1, acc1, 0, 0, 0);
    }

    // ---- hpT2 chunk-tiled f16 [b][cj][o][8]: lane holds 4 CONSECUTIVE rows ----
    const int b   = R0 >> 11;
    const int jb0 = (R0 & 2047) + rt * 16 + g * 4;
    const int cj  = jb0 >> 3;
    const int sub = jb0 & 7;             // 0 or 4
    unsigned short* cbase = hpT2 + (((size_t)(b * 256 + cj)) * OUTD) * 8;
    {
        ushort4 u;
        u.x = f2h(acc0[0]); u.y = f2h(acc0[1]);
        u.z = f2h(acc0[2]); u.w = f2h(acc0[3]);
        *(ushort4*)(cbase + o_0 * 8 + sub) = u;
        u.x = f2h(acc1[0]); u.y = f2h(acc1[1]);
        u.z = f2h(acc1[2]); u.w = f2h(acc1[3]);
        *(ushort4*)(cbase + o_1 * 8 + sub) = u;
    }

    // ---- s, d partials over this wave's 32 cols, reduce across 16 lanes ----
    const float a_s0 = asrc[o_0], a_s1 = asrc[o_1];
    const float a_d0 = adst[o_0], a_d1 = adst[o_1];
    float ps[4], pd[4];
    #pragma unroll
    for (int r = 0; r < 4; ++r) {
        ps[r] = acc0[r] * a_s0 + acc1[r] * a_s1;
        pd[r] = acc0[r] * a_d0 + acc1[r] * a_d1;
    }
    #pragma unroll
    for (int msk = 1; msk <= 8; msk <<= 1) {
        #pragma unroll
        for (int r = 0; r < 4; ++r) {
            ps[r] += __shfl_xor(ps[r], msk);
            pd[r] += __shfl_xor(pd[r], msk);
        }
    }
    if (m == 0) {
        #pragma unroll
        for (int r = 0; r < 4; ++r) {
            const int row = rt * 16 + g * 4 + r;
            sps[row][nh] = ps[r];
            spd[row][nh] = pd[r];
        }
    }
    __syncthreads();
    if (t < 64) {
        const float sv = sps[t][0] + sps[t][1];
        const float dv = spd[t][0] + spd[t][1];
        s[R0 + t] = sv;
        F[R0 + t] = (_Float16)__expf(dv);
        H[R0 + t] = (_Float16)__expf(NEG * dv);
    }
}

// ---------------------------------------------------------------------------
// Kernel 2: softmax(leakyrelu(s_i+d_j+b)) @ hp via f16 MFMA.
// OCCUPANCY FIX: i-tile 64 -> 32 rows, grid 256 -> 512, LDS 74 -> 38 KB
// => 2 blocks/CU, 4 waves/SIMD (was 1 block, 2 waves/SIMD). Prologue exp,
// B-frag L2 latency and barrier-fenced epilogue now covered by 2x the waves;
// one block's epilogue overlaps the other's main loop. Per wave: 2 A-tiles
// (32 rows) x 256-j range; same 16 iters, half the MFMA per iter against the
// same 6 loads — fine once latency is hidden. Aggregate L2 reads double
// (hpT2 read per 32-row block) but stay ~1.6us/CU, hidden.
// Weights exp(leaky(x)) = max(E_i*F_j, G_i*H_j) in packed f16 (result IS the
// MFMA A-frag); denominator via ones-B MFMA; b128 permuted LDS combine.
// ---------------------------------------------------------------------------
__global__ __launch_bounds__(512) void gat_attn_kernel(
    const unsigned short* __restrict__ hpT2, const float* __restrict__ s,
    const _Float16* __restrict__ F, const _Float16* __restrict__ H,
    const float* __restrict__ battn_p, float* __restrict__ out)
{
    __shared__ float accl[4][32 * 72];   // 36.9 KB, permuted [row][m*4+ot]
    __shared__ float ll[8][32];          // per-wave denominator partials
    __shared__ float llsum[32];          // folded denominators

    const int t    = threadIdx.x;
    const int lane = t & 63;
    const int wv   = t >> 6;             // 0..7
    const int blk  = blockIdx.x;         // 0..511
    const int b    = blk >> 6;           // 64 row-groups per batch
    const int i0   = (blk & 63) * 32;
    const int m    = lane & 15;
    const int kc   = lane >> 4;          // k-chunk quad (0..3)

    const float battn = battn_p[0];
    h2 E2[2], G2[2];
    #pragma unroll
    for (int T = 0; T < 2; ++T) {
        const float smv = s[b * NN + i0 + T * 16 + m] + battn;
        const float Ef = __expf(smv);
        const float Gf = __expf(NEG * smv);
        E2[T] = (h2){(_Float16)Ef, (_Float16)Ef};
        G2[T] = (h2){(_Float16)Gf, (_Float16)Gf};
    }
    const _Float16* Fb = F + b * NN;
    const _Float16* Hb = H + b * NN;
    const _Float16* hb = (const _Float16*)hpT2 + (size_t)b * 256 * OUTD * 8;

    half8 ones;
    #pragma unroll
    for (int q = 0; q < 8; ++q) ones[q] = (_Float16)1.0f;

    f32x4 acc[2][4];                     // [tile][ot]
    f32x4 dacc[2];                       // [tile] denominator
    #pragma unroll
    for (int T = 0; T < 2; ++T) {
        dacc[T] = (f32x4){0.f, 0.f, 0.f, 0.f};
        #pragma unroll
        for (int ot = 0; ot < 4; ++ot) acc[T][ot] = (f32x4){0.f, 0.f, 0.f, 0.f};
    }

    const int jbase = wv * (NN / 8);     // this wave's 256-wide j range

    #pragma unroll 2
    for (int it = 0; it < NN / 8 / 32; ++it) {
        const int j0 = jbase + it * 32;
        // --- B-frags first (longest latency): hp[j0+kc*8..+7][ot*16+m] ---
        const size_t cb = ((size_t)((j0 >> 3) + kc)) * OUTD * 8;
        const half8 bf0 = *(const half8*)(hb + cb + (0 * 16 + m) * 8);
        const half8 bf1 = *(const half8*)(hb + cb + (1 * 16 + m) * 8);
        const half8 bf2 = *(const half8*)(hb + cb + (2 * 16 + m) * 8);
        const half8 bf3 = *(const half8*)(hb + cb + (3 * 16 + m) * 8);

        union { float4 q; h2 p[4]; } Ff, Hf;
        Ff.q = *(const float4*)(Fb + j0 + kc * 8);   // 8 f16 F values
        Hf.q = *(const float4*)(Hb + j0 + kc * 8);   // 8 f16 H values

        #pragma unroll
        for (int T = 0; T < 2; ++T) {
            union { half8 v; h2 p[4]; } af;
            af.p[0] = __builtin_elementwise_max(E2[T] * Ff.p[0], G2[T] * Hf.p[0]);
            af.p[1] = __builtin_elementwise_max(E2[T] * Ff.p[1], G2[T] * Hf.p[1]);
            af.p[2] = __builtin_elementwise_max(E2[T] * Ff.p[2], G2[T] * Hf.p[2]);
            af.p[3] = __builtin_elementwise_max(E2[T] * Ff.p[3], G2[T] * Hf.p[3]);

            acc[T][0] = __builtin_amdgcn_mfma_f32_16x16x32_f16(af.v, bf0, acc[T][0], 0, 0, 0);
            acc[T][1] = __builtin_amdgcn_mfma_f32_16x16x32_f16(af.v, bf1, acc[T][1], 0, 0, 0);
            acc[T][2] = __builtin_amdgcn_mfma_f32_16x16x32_f16(af.v, bf2, acc[T][2], 0, 0, 0);
            acc[T][3] = __builtin_amdgcn_mfma_f32_16x16x32_f16(af.v, bf3, acc[T][3], 0, 0, 0);
            dacc[T]   = __builtin_amdgcn_mfma_f32_16x16x32_f16(af.v, ones, dacc[T], 0, 0, 0);
        }
    }

    // denominator partials: D column 0 lives in m==0 lanes; row = kc*4 + reg
    if (m == 0) {
        #pragma unroll
        for (int T = 0; T < 2; ++T)
            #pragma unroll
            for (int r = 0; r < 4; ++r) ll[wv][T * 16 + kc * 4 + r] = dacc[T][r];
    }

    // ---- two-stage combine, b128 permuted layout [row][m*4+ot] ----
    if (wv >= 4) {
        #pragma unroll
        for (int T = 0; T < 2; ++T) {
            #pragma unroll
            for (int r = 0; r < 4; ++r) {
                const int row = T * 16 + kc * 4 + r;
                float4 v;
                v.x = acc[T][0][r]; v.y = acc[T][1][r];
                v.z = acc[T][2][r]; v.w = acc[T][3][r];
                *(float4*)&accl[wv - 4][row * 72 + m * 4] = v;
            }
        }
    }
    __syncthreads();
    if (wv < 4) {
        #pragma unroll
        for (int T = 0; T < 2; ++T) {
            #pragma unroll
            for (int r = 0; r < 4; ++r) {
                const int row = T * 16 + kc * 4 + r;
                float4 v = *(const float4*)&accl[wv][row * 72 + m * 4];
                v.x += acc[T][0][r]; v.y += acc[T][1][r];
                v.z += acc[T][2][r]; v.w += acc[T][3][r];
                *(float4*)&accl[wv][row * 72 + m * 4] = v;
            }
        }
    }
    // wave 0 folds the 8 denominator partials per row (overlaps waves 1-3)
    if (t < 32) {
        llsum[t] = ((ll[0][t] + ll[1][t]) + (ll[2][t] + ll[3][t])) +
                   ((ll[4][t] + ll[5][t]) + (ll[6][t] + ll[7][t]));
    }
    __syncthreads();

    // ---- epilogue: b128 reads, divide, ELU, coalesced stores ----
    // 512 threads = 32 rows x 16 q-groups; stored idx q*4+ot -> col ot*16+q
    const int q   = t & 15;
    const int row = t >> 4;              // 0..31
    float* ob = out + (((size_t)b * NN + i0) * OUTD);
    {
        const float4 v0 = *(const float4*)&accl[0][row * 72 + q * 4];
        const float4 v1 = *(const float4*)&accl[1][row * 72 + q * 4];
        const float4 v2 = *(const float4*)&accl[2][row * 72 + q * 4];
        const float4 v3 = *(const float4*)&accl[3][row * 72 + q * 4];
        const float ls = llsum[row];
        float vv[4];
        vv[0] = (v0.x + v1.x) + (v2.x + v3.x);
        vv[1] = (v0.y + v1.y) + (v2.y + v3.y);
        vv[2] = (v0.z + v1.z) + (v2.z + v3.z);
        vv[3] = (v0.w + v1.w) + (v2.w + v3.w);
        #pragma unroll
        for (int ot = 0; ot < 4; ++ot) {
            float v = vv[ot] / ls;
            v = (v > 0.f) ? v : expm1f(v);
            ob[(size_t)row * OUTD + ot * 16 + q] = v;
        }
    }
}

// ---------------------------------------------------------------------------
extern "C" void kernel_launch(void* const* d_in, const int* in_sizes, int n_in,
                              void* d_out, int out_size, void* d_ws, size_t ws_size,
                              hipStream_t stream)
{
    const float* h     = (const float*)d_in[0];
    const float* W     = (const float*)d_in[1];
    const float* bfc   = (const float*)d_in[2];
    const float* asrc  = (const float*)d_in[3];
    const float* adst  = (const float*)d_in[4];
    const float* battn = (const float*)d_in[5];
    float* out = (float*)d_out;

    unsigned short* hpT2 = (unsigned short*)d_ws;            // 2 MB f16 tiled
    float*     s = (float*)((char*)d_ws + (size_t)BB * NN * OUTD * 2);
    _Float16*  F = (_Float16*)(s + (size_t)BB * NN);
    _Float16*  H = F + (size_t)BB * NN;

    gat_proj_kernel<<<(BB * NN) / 64, 512, 0, stream>>>(h, W, bfc, asrc, adst,
                                                        hpT2, s, F, H);
    gat_attn_kernel<<<BB * (NN / 32), 512, 0, stream>>>(hpT2, s, F, H, battn, out);
}